// Round 5
// baseline (198.750 us; speedup 1.0000x reference)
//
#include <hip/hip_runtime.h>

typedef __attribute__((ext_vector_type(8))) short bf16x8;
typedef __attribute__((ext_vector_type(4))) float f32x4;
typedef __attribute__((ext_vector_type(16))) float f32x16;

#define M_TOT 8192
#define N_TOT 8192
#define K_TOT 256

// ---------- helpers ----------
__device__ __forceinline__ unsigned short f2bf(float f) {
  unsigned u = __float_as_uint(f);
  unsigned r = (u + 0x7FFFu + ((u >> 16) & 1u)) >> 16;  // RNE, no NaN in data
  return (unsigned short)r;
}
__device__ __forceinline__ float bf2f(unsigned short h) {
  return __uint_as_float(((unsigned)h) << 16);
}
__device__ __forceinline__ unsigned long long shfl_xor_u64(unsigned long long v, int m) {
  unsigned lo = (unsigned)v, hi = (unsigned)(v >> 32);
  lo = __shfl_xor(lo, m, 64);
  hi = __shfl_xor(hi, m, 64);
  return (((unsigned long long)hi) << 32) | lo;
}
__device__ __forceinline__ void load_lds16(const void* g, void* l) {
  __builtin_amdgcn_global_load_lds(
      (const __attribute__((address_space(1))) unsigned int*)g,
      (__attribute__((address_space(3))) unsigned int*)l, 16, 0, 0);
}

// ---------- fused prep: split-2 of x AND embed, + ||e||^2, + key init ----------
__global__ __launch_bounds__(256) void prep_kernel(
    const float* __restrict__ x, const float* __restrict__ embed,
    unsigned short* __restrict__ X0, unsigned short* __restrict__ X1,
    unsigned short* __restrict__ E0, unsigned short* __restrict__ E1,
    float* __restrict__ esq, unsigned long long* __restrict__ keys) {
  const int bid = blockIdx.x;
  const bool is_e = bid >= 2048;
  const int lb = is_e ? bid - 2048 : bid;
  const int t = lb * 256 + threadIdx.x;
  if (bid < 32) keys[t] = ~0ULL;  // 8192 keys

  const float* __restrict__ in = is_e ? embed : x;
  unsigned short* __restrict__ s0 = is_e ? E0 : X0;
  unsigned short* __restrict__ s1 = is_e ? E1 : X1;

  float4 v = reinterpret_cast<const float4*>(in)[t];
  float f[4] = {v.x, v.y, v.z, v.w};
  unsigned short a0[4], a1[4];
#pragma unroll
  for (int c = 0; c < 4; ++c) {
    unsigned short b0 = f2bf(f[c]);
    a0[c] = b0;
    a1[c] = f2bf(f[c] - bf2f(b0));  // residual exact
  }
  ushort4 o0 = {a0[0], a0[1], a0[2], a0[3]};
  ushort4 o1 = {a1[0], a1[1], a1[2], a1[3]};
  reinterpret_cast<ushort4*>(s0)[t] = o0;
  reinterpret_cast<ushort4*>(s1)[t] = o1;

  if (is_e) {
    const int lane = threadIdx.x & 63;
    float s = f[0] * f[0] + f[1] * f[1] + f[2] * f[2] + f[3] * f[3];
#pragma unroll
    for (int off = 32; off > 0; off >>= 1) s += __shfl_xor(s, off, 64);
    if (lane == 0) esq[lb * 4 + (threadIdx.x >> 6)] = s;  // wave == e-row
  }
}

// ---------- fused split-2 bf16 MFMA dist-GEMM + argmin ----------
// Block tile 128M x 256N, 4 waves 2x2, wave tile 64x128 = 2x4 tiles of 32x32.
// MFMA v_mfma_f32_32x32x16_bf16 (ceiling 2495 TF vs ~2100 for 16x16x32).
// 3 split-passes: x0e0, x0e1, x1e0. LDS 48 KB: X0,X1 (8 segs each), E0,E1
// (16 segs each); seg = 16 rows x 32 k, swizzled so both global_load_lds
// staging and 32-row frag ds_read_b128 are bank-uniform (r2-r4: 0 conflicts).
// (256,2): cap 256 regs, need ~216 (acc 128 + afr 32 + misc) -> no spill.
// Round-3 lesson: a spilled accumulator = 2.9 GB scratch traffic; watch WRITE_SIZE.
__global__ __launch_bounds__(256, 2) void mfma_argmin_kernel(
    const unsigned short* __restrict__ X0, const unsigned short* __restrict__ X1,
    const unsigned short* __restrict__ E0, const unsigned short* __restrict__ E1,
    const float* __restrict__ esq, unsigned long long* __restrict__ keys) {
  __shared__ unsigned short lds[24576];  // 48 KB

  const int tid = threadIdx.x;
  const int wid = tid >> 6;
  const int lane = tid & 63;
  const int li = lane & 15;
  const int lh = (lane >> 4) & 1;  // seg half within 32-row tile
  const int lq2 = lane >> 5;       // k-group within frag

  // XCD-sharded N: blocks with same (bid&7) share an E-slice (L2-resident)
  const int bid = blockIdx.x;
  const int nb = (bid & 7) * 4 + ((bid >> 3) & 3);  // 0..31
  const int mb = bid >> 5;                          // 0..63
  const int m0 = mb * 128, n0 = nb * 256;
  const int wm = (wid >> 1) * 64, wn = (wid & 1) * 128;

  // staging: lane -> (row-in-segment, k-part) inverse swizzle
  const int r_st = lane >> 2;
  const int kp_st = ((lane & 3) - (r_st >> 1)) & 3;
  // frag read swizzle (ushort offset within seg), for k-slice 0 and 1
  const int sw_k0 = (li * 4 + ((lq2 + (li >> 1)) & 3)) * 8;
  const int sw_k1 = (li * 4 + ((2 + lq2 + (li >> 1)) & 3)) * 8;

  f32x16 acc[2][4];
#pragma unroll
  for (int a = 0; a < 2; ++a)
#pragma unroll
    for (int b = 0; b < 4; ++b)
#pragma unroll
      for (int r = 0; r < 16; ++r) acc[a][b][r] = 0.0f;

  const int aseg = (wm >> 4) + lh;         // + mt*2
  const int bseg = (wn >> 4) + lh;         // + nt*2

  for (int kc = 0; kc < 8; ++kc) {
    const int k0 = kc * 32;
    __syncthreads();
    // stage 48 KB: X0,X1 8 segs each; E0,E1 16 segs each (48 seg-loads / 4 waves)
#pragma unroll
    for (int j = 0; j < 12; ++j) {
      const int tt = j * 4 + wid;  // wave-uniform
      const unsigned short* src;
      int row, lbase;
      if (tt < 16) {
        const int tsel = tt >> 3;  // 0=X0 1=X1
        const int seg = tt & 7;
        src = tsel ? X1 : X0;
        row = m0 + seg * 16 + r_st;
        lbase = tsel * 4096 + seg * 512;
      } else {
        const int u = tt - 16;
        const int sp = u >> 4;     // 0=E0 1=E1
        const int seg = u & 15;
        src = sp ? E1 : E0;
        row = n0 + seg * 16 + r_st;
        lbase = 8192 + sp * 8192 + seg * 512;
      }
      load_lds16(src + (size_t)row * K_TOT + k0 + kp_st * 8, &lds[lbase]);
    }
    __syncthreads();

    // A-frags: [split][mt][ks]
    bf16x8 afr[2][2][2];
#pragma unroll
    for (int s = 0; s < 2; ++s)
#pragma unroll
      for (int mt = 0; mt < 2; ++mt) {
        const unsigned short* ab = &lds[s * 4096 + (aseg + mt * 2) * 512];
        afr[s][mt][0] = *(const bf16x8*)(ab + sw_k0);
        afr[s][mt][1] = *(const bf16x8*)(ab + sw_k1);
      }

#pragma unroll
    for (int nt = 0; nt < 4; ++nt) {
      const unsigned short* b0b = &lds[8192 + (bseg + nt * 2) * 512];
      const unsigned short* b1b = b0b + 8192;
      bf16x8 b00 = *(const bf16x8*)(b0b + sw_k0);  // E0, ks0
      bf16x8 b01 = *(const bf16x8*)(b0b + sw_k1);  // E0, ks1
      bf16x8 b10 = *(const bf16x8*)(b1b + sw_k0);  // E1, ks0
      bf16x8 b11 = *(const bf16x8*)(b1b + sw_k1);  // E1, ks1
#pragma unroll
      for (int mt = 0; mt < 2; ++mt) {
        f32x16 c = acc[mt][nt];
        c = __builtin_amdgcn_mfma_f32_32x32x16_bf16(afr[0][mt][0], b00, c, 0, 0, 0);
        c = __builtin_amdgcn_mfma_f32_32x32x16_bf16(afr[0][mt][1], b01, c, 0, 0, 0);
        c = __builtin_amdgcn_mfma_f32_32x32x16_bf16(afr[0][mt][0], b10, c, 0, 0, 0);
        c = __builtin_amdgcn_mfma_f32_32x32x16_bf16(afr[0][mt][1], b11, c, 0, 0, 0);
        c = __builtin_amdgcn_mfma_f32_32x32x16_bf16(afr[1][mt][0], b00, c, 0, 0, 0);
        c = __builtin_amdgcn_mfma_f32_32x32x16_bf16(afr[1][mt][1], b01, c, 0, 0, 0);
        acc[mt][nt] = c;
      }
    }
  }

  // ---- argmin epilogue: dist = ||e||^2 - 2 x.e ----
  // 32x32 C/D layout (m74/m101): col = lane&31, row = (r&3)+8*(r>>2)+4*(lane>>5)
  const int colbase = n0 + wn + (lane & 31);
  float ev[4];
#pragma unroll
  for (int nt = 0; nt < 4; ++nt) ev[nt] = esq[colbase + nt * 32];

#pragma unroll
  for (int mt = 0; mt < 2; ++mt) {
#pragma unroll
    for (int r = 0; r < 16; ++r) {
      unsigned long long best = ~0ULL;
#pragma unroll
      for (int nt = 0; nt < 4; ++nt) {
        float d = fmaxf(ev[nt] - 2.0f * acc[mt][nt][r], 0.0f);  // >=0 -> bits order-preserving
        unsigned long long key =
            (((unsigned long long)__float_as_uint(d)) << 32) | (unsigned)(colbase + nt * 32);
        best = key < best ? key : best;
      }
#pragma unroll
      for (int off = 1; off < 32; off <<= 1) {  // reduce over 32 col-lanes
        unsigned long long o = shfl_xor_u64(best, off);
        best = o < best ? o : best;
      }
      if ((lane & 31) == 0) {
        const int m = m0 + wm + mt * 32 + (r & 3) + 8 * (r >> 2) + 4 * lq2;
        atomicMin(&keys[m], best);  // tie -> lower idx = first occurrence
      }
    }
  }
}

// ---------- gather + index write (4 rows per block) ----------
__global__ __launch_bounds__(256) void gather2_kernel(const float* __restrict__ embed,
                                                      const unsigned long long* __restrict__ keys,
                                                      float* __restrict__ out) {
  const int row = blockIdx.x * 4 + (threadIdx.x >> 6);
  const int lane = threadIdx.x & 63;
  const unsigned idx = (unsigned)keys[row];
  reinterpret_cast<float4*>(out)[(size_t)row * 64 + lane] =
      reinterpret_cast<const float4*>(embed)[(size_t)idx * 64 + lane];
  if (lane == 0) out[(size_t)M_TOT * K_TOT + row] = (float)idx;
}

// ================= fallback (round-1 fp32 path, known-correct) =================
#define BM 32
#define BN 64
#define KC 32
#define NQ 2
#define NPQ (N_TOT / NQ)
#define SB 72

__global__ __launch_bounds__(256) void esq_kernel(const float* __restrict__ embed,
                                                  float* __restrict__ esq) {
  const int lane = threadIdx.x & 63;
  const int wave = threadIdx.x >> 6;
  const int code = blockIdx.x * 4 + wave;
  float4 v = reinterpret_cast<const float4*>(embed + (size_t)code * K_TOT)[lane];
  float s = v.x * v.x + v.y * v.y + v.z * v.z + v.w * v.w;
#pragma unroll
  for (int off = 32; off > 0; off >>= 1) s += __shfl_xor(s, off, 64);
  if (lane == 0) esq[code] = s;
}

__global__ __launch_bounds__(256, 2) void argmin_kernel(
    const float* __restrict__ x, const float* __restrict__ embed,
    const float* __restrict__ esq, float* __restrict__ pval, int* __restrict__ pidx) {
  __shared__ float A[K_TOT][BM];
  __shared__ float Bs[KC][SB];
  const int tid = threadIdx.x;
  const int tx = tid & 15;
  const int ty = tid >> 4;
  const int q = blockIdx.x & 1;
  const int mb = blockIdx.x >> 1;
  const int m0 = mb * BM;
  const int nq0 = q * NPQ;
#pragma unroll
  for (int it = 0; it < 8; ++it) {
    int idx = it * 256 + tid;
    int row = idx >> 6;
    int k4 = idx & 63;
    float4 v = reinterpret_cast<const float4*>(x + (size_t)(m0 + row) * K_TOT)[k4];
    A[k4 * 4 + 0][row] = v.x; A[k4 * 4 + 1][row] = v.y;
    A[k4 * 4 + 2][row] = v.z; A[k4 * 4 + 3][row] = v.w;
  }
  float minv[2]; int mini[2];
#pragma unroll
  for (int r = 0; r < 2; ++r) { minv[r] = 3.4e38f; mini[r] = 0; }
  for (int ns = 0; ns < NPQ / BN; ++ns) {
    const int n0 = nq0 + ns * BN;
    float acc[2][4];
#pragma unroll
    for (int r = 0; r < 2; ++r)
#pragma unroll
      for (int c = 0; c < 4; ++c) acc[r][c] = 0.0f;
    for (int kc = 0; kc < K_TOT / KC; ++kc) {
      const int k0 = kc * KC;
      __syncthreads();
#pragma unroll
      for (int it = 0; it < 2; ++it) {
        int idx = it * 256 + tid;
        int nl = idx >> 3;
        int k4 = idx & 7;
        float4 v = reinterpret_cast<const float4*>(embed + (size_t)(n0 + nl) * K_TOT + k0)[k4];
        Bs[k4 * 4 + 0][nl] = v.x; Bs[k4 * 4 + 1][nl] = v.y;
        Bs[k4 * 4 + 2][nl] = v.z; Bs[k4 * 4 + 3][nl] = v.w;
      }
      __syncthreads();
#pragma unroll
      for (int kk = 0; kk < KC; ++kk) {
        float2 a = *reinterpret_cast<const float2*>(&A[k0 + kk][ty * 2]);
        float4 b = *reinterpret_cast<const float4*>(&Bs[kk][tx * 4]);
        acc[0][0] += a.x * b.x; acc[0][1] += a.x * b.y;
        acc[0][2] += a.x * b.z; acc[0][3] += a.x * b.w;
        acc[1][0] += a.y * b.x; acc[1][1] += a.y * b.y;
        acc[1][2] += a.y * b.z; acc[1][3] += a.y * b.w;
      }
    }
    float4 es = *reinterpret_cast<const float4*>(&esq[n0 + tx * 4]);
    float e[4] = {es.x, es.y, es.z, es.w};
#pragma unroll
    for (int r = 0; r < 2; ++r)
#pragma unroll
      for (int c = 0; c < 4; ++c) {
        float d = e[c] - 2.0f * acc[r][c];
        int id = n0 + tx * 4 + c;
        if (d < minv[r]) { minv[r] = d; mini[r] = id; }
      }
  }
#pragma unroll
  for (int r = 0; r < 2; ++r) {
    float v = minv[r]; int i = mini[r];
#pragma unroll
    for (int off = 1; off < 16; off <<= 1) {
      float vo = __shfl_xor(v, off, 64);
      int io = __shfl_xor(i, off, 64);
      if (vo < v || (vo == v && io < i)) { v = vo; i = io; }
    }
    if (tx == 0) {
      int row = m0 + ty * 2 + r;
      pval[q * M_TOT + row] = v;
      pidx[q * M_TOT + row] = i;
    }
  }
}

__global__ __launch_bounds__(256) void gather_kernel(
    const float* __restrict__ embed, const float* __restrict__ pval,
    const int* __restrict__ pidx, float* __restrict__ out) {
  const int row = blockIdx.x;
  float bv = pval[row]; int bi = pidx[row];
#pragma unroll
  for (int qq = 1; qq < NQ; ++qq) {
    float v = pval[qq * M_TOT + row];
    int i = pidx[qq * M_TOT + row];
    if (v < bv || (v == bv && i < bi)) { bv = v; bi = i; }
  }
  out[(size_t)row * K_TOT + threadIdx.x] = embed[(size_t)bi * K_TOT + threadIdx.x];
  if (threadIdx.x == 0) out[(size_t)M_TOT * K_TOT + row] = (float)bi;
}

// ================= launch =================
extern "C" void kernel_launch(void* const* d_in, const int* in_sizes, int n_in,
                              void* d_out, int out_size, void* d_ws, size_t ws_size,
                              hipStream_t stream) {
  const float* x = (const float*)d_in[0];
  const float* embed = (const float*)d_in[1];
  float* out = (float*)d_out;
  char* ws = (char*)d_ws;

  const size_t SPLIT_BYTES = (size_t)M_TOT * K_TOT * 2;  // 4 MB per split matrix
  const size_t need = (1u << 20) + 4 * SPLIT_BYTES;      // ~17.8 MB

  if (ws_size >= need) {
    unsigned long long* keys = (unsigned long long*)ws;  // 64 KB
    float* esq = (float*)(ws + 65536);                   // 32 KB
    unsigned short* S[4];
    for (int i = 0; i < 4; ++i) S[i] = (unsigned short*)(ws + (1u << 20) + i * SPLIT_BYTES);
    prep_kernel<<<4096, 256, 0, stream>>>(x, embed, S[0], S[1], S[2], S[3], esq, keys);
    mfma_argmin_kernel<<<2048, 256, 0, stream>>>(S[0], S[1], S[2], S[3], esq, keys);
    gather2_kernel<<<2048, 256, 0, stream>>>(embed, keys, out);
  } else {
    float* esq = (float*)ws;
    float* pval = (float*)(ws + 32768);
    int* pidx = (int*)(ws + 32768 + NQ * 32768);
    esq_kernel<<<2048, 256, 0, stream>>>(embed, esq);
    argmin_kernel<<<512, 256, 0, stream>>>(x, embed, esq, pval, pidx);
    gather_kernel<<<M_TOT, 256, 0, stream>>>(embed, pval, pidx, out);
  }
}